// Round 1
// 789.756 us; speedup vs baseline: 1.2306x; 1.2306x over previous
//
#include <hip/hip_runtime.h>
#include <hip/hip_bf16.h>
#include <stdint.h>
#include <stddef.h>

typedef __bf16 bf16;
typedef bf16  bf16x4 __attribute__((ext_vector_type(4)));
typedef bf16  bf16x8 __attribute__((ext_vector_type(8)));
typedef float f32x4  __attribute__((ext_vector_type(4)));

// ---------------------------------------------------------------------------
// async global->LDS, 16B per lane. LDS dest is wave-uniform base + lane*16.
// ---------------------------------------------------------------------------
__device__ __forceinline__ void async_copy16(bf16* lds, const bf16* g) {
    __builtin_amdgcn_global_load_lds(
        (const __attribute__((address_space(1))) void*)g,
        (__attribute__((address_space(3))) void*)lds,
        16, 0, 0);
}

// raw barrier + compiler memory fence (NO vmcnt drain — that is the point).
// The asm("" memory) fences stop the compiler from hoisting ds_reads /
// global_load_lds across the barrier (s_barrier builtin alone is not a
// guaranteed IR-level memory fence).
__device__ __forceinline__ void fence_barrier() {
    asm volatile("" ::: "memory");
    __builtin_amdgcn_s_barrier();
    asm volatile("" ::: "memory");
}
#define LGKM0() asm volatile("s_waitcnt lgkmcnt(0)" ::: "memory")

// ---------------------------------------------------------------------------
// cast fp32 -> bf16, 4 elems/thread (unchanged)
// ---------------------------------------------------------------------------
__global__ __launch_bounds__(256) void cast_f32_to_bf16(
        const float* __restrict__ in, bf16* __restrict__ out, int n4) {
    int i = blockIdx.x * blockDim.x + threadIdx.x;
    if (i >= n4) return;
    const float4 v = *(const float4*)(in + (size_t)i * 4);
    bf16x4 o;
    o[0] = (bf16)v.x; o[1] = (bf16)v.y; o[2] = (bf16)v.z; o[3] = (bf16)v.w;
    *(bf16x4*)(out + (size_t)i * 4) = o;
}

// ---------------------------------------------------------------------------
// W_eff[n][k] = (q[n][k] - 7.5) * scale[n][k/64] + sum_r A[k][r]*Bm[r][n]
// (unchanged — measured ~50 us total for both dispatches)
// ---------------------------------------------------------------------------
__global__ __launch_bounds__(256) void dequant_lora(
        const int*   __restrict__ q,
        const float* __restrict__ scale,
        const float* __restrict__ A,
        const float* __restrict__ Bm,
        bf16* __restrict__ out,
        int N, int K) {
    const int tid = threadIdx.x;
    const int k0 = blockIdx.x * 64;
    const int n0 = blockIdx.y * 64;
    const int kk = k0 + (tid & 15) * 4;
    const int nb = n0 + (tid >> 4) * 4;

    f32x4 Ar[4][4];
    #pragma unroll
    for (int i = 0; i < 4; ++i)
        #pragma unroll
        for (int rq = 0; rq < 4; ++rq)
            Ar[i][rq] = *(const f32x4*)&A[(size_t)(kk + i) * 16 + rq * 4];
    f32x4 Br[16];
    #pragma unroll
    for (int r = 0; r < 16; ++r)
        Br[r] = *(const f32x4*)&Bm[(size_t)r * N + nb];

    const int scol = (unsigned)k0 >> 6;
    #pragma unroll
    for (int nn = 0; nn < 4; ++nn) {
        const int n = nb + nn;
        const int4 qv = *(const int4*)&q[(size_t)n * K + kk];
        const float s = scale[(size_t)n * (K >> 6) + scol];
        float l0 = 0.f, l1 = 0.f, l2 = 0.f, l3 = 0.f;
        #pragma unroll
        for (int r = 0; r < 16; ++r) {
            const float bv = Br[r][nn];
            l0 += Ar[0][r >> 2][r & 3] * bv;
            l1 += Ar[1][r >> 2][r & 3] * bv;
            l2 += Ar[2][r >> 2][r & 3] * bv;
            l3 += Ar[3][r >> 2][r & 3] * bv;
        }
        bf16x4 o;
        o[0] = (bf16)(((float)qv.x - 7.5f) * s + l0);
        o[1] = (bf16)(((float)qv.y - 7.5f) * s + l1);
        o[2] = (bf16)(((float)qv.z - 7.5f) * s + l2);
        o[3] = (bf16)(((float)qv.w - 7.5f) * s + l3);
        *(bf16x4*)&out[(size_t)n * K + kk] = o;
    }
}

// ---------------------------------------------------------------------------
// gemm_bt256: C[m][n] = sum_k A[m][k]*B[n][k] + bias[n]  (optional ReLU)
//
// v5: 256x256 tile, BK=64, 8 waves (2Mx4N), 8-phase schedule with counted
// vmcnt (T2+T3+T4+T5 stack; m201 template, 1563 TF @4k reference).
//
// LDS: [dbuf 2][half 2][128x64] bf16 for A and B = 128 KiB, 1 block/CU.
// Each half-tile is 128 rows x 64 k. Swizzle: 16B-granule column index is
// XORed with (row&7) — an involution, applied BOTH on the global source
// address at staging (LDS dest stays linear: global_load_lds requirement)
// and on the ds_read address. Kills the stride-128B same-bank column
// (SQ_LDS_BANK_CONFLICT 3.4e7 -> ~0 expected).
//
// Per K-tile t (group = 4 phases; wave owns 128x64 out = acc[8][4]):
//   p1: ds_read fa(m0-3,ks0/1)+fb(all 8) | stage A-hi(t+1) | MFMA Q0(i0-3,j0-1)
//   p2:                                  | stage B-lo(t+2) | MFMA Q1(i0-3,j2-3)
//   p3: ds_read fa(m4-7)                 | stage B-hi(t+2) | MFMA Q2(i4-7,j2-3)
//   p4:                  | stage A-lo(t+2) + vmcnt(6)      | MFMA Q3(i4-7,j0-1)
// Each phase: {reads, stage} -> barrier -> lgkmcnt(0) -> setprio(1) ->
// 16 MFMA -> setprio(0) -> barrier.  The mid-phase lgkmcnt(0) drains reads
// not consumed this phase (fb23 at p1) so the end barrier publishes
// "this buffer region is re-stageable".  vmcnt(6) once per K-tile keeps
// 3 half-tiles (6 loads) in flight ACROSS barriers — never drains to 0
// until the tail.  Safety: B-halves of buf p fully read by end p1, A-halves
// by end p3; stages into them issue >= one end-barrier later.
// ---------------------------------------------------------------------------
template <bool RELU, typename OUT_T>
__global__ __launch_bounds__(512, 2) void gemm_bt256(
        const bf16* __restrict__ A, const bf16* __restrict__ B,
        const float* __restrict__ bias, OUT_T* __restrict__ C,
        int M, int N, int K) {
    __shared__ __attribute__((aligned(16))) bf16 As[2][2][128 * 64];
    __shared__ __attribute__((aligned(16))) bf16 Bs[2][2][128 * 64];

    const int tid  = threadIdx.x;
    const int wave = tid >> 6;
    const int lane = tid & 63;
    const int wm   = wave >> 2;     // 0..1 : row half of the 256-tile
    const int wn   = wave & 3;      // 0..3 : 64-col slice
    const int bn   = blockIdx.x;
    const int bm   = blockIdx.y;

    // staging: thread covers 16B-granules tid (rows 0..63) and tid+512
    // (rows 64..127) of each [128][64] half-tile. Source column granule is
    // pre-swizzled: cg = (tid&7) ^ (row&7)  (row&7 == srow&7 for both loads).
    const int srow = tid >> 3;
    const int scol = ((tid & 7) ^ (srow & 7)) * 8;   // elems
    const bf16* gA = A + ((size_t)(bm * 256) + srow) * K + scol;
    const bf16* gB = B + ((size_t)(bn * 256) + srow) * K + scol;

    auto STAGE_A = [&](int h, int tt) {
        bf16* l = &As[tt & 1][h][wave * 512];        // wave-uniform dest
        const bf16* g = gA + (size_t)h * 128 * K + (size_t)tt * 64;
        async_copy16(l, g);
        async_copy16(l + 4096, g + (size_t)64 * K);  // rows +64
    };
    auto STAGE_B = [&](int h, int tt) {
        bf16* l = &Bs[tt & 1][h][wave * 512];
        const bf16* g = gB + (size_t)h * 128 * K + (size_t)tt * 64;
        async_copy16(l, g);
        async_copy16(l + 4096, g + (size_t)64 * K);
    };

    // ds_read fragment addressing (within a [128][64] half, elems), with the
    // same involution on the column granule: cg(ks) = ((ks*4+kq) ^ (fr&7))*8.
    const int fr  = lane & 15;
    const int kq  = lane >> 4;
    const int cg0 = ((kq    ) ^ (fr & 7)) * 8;
    const int cg1 = ((kq + 4) ^ (fr & 7)) * 8;
    const int ra  = fr * 64;
    const int rb  = (wn & 1) * 4096 + fr * 64;       // 64-col offset in B half

    f32x4 acc[8][4];
    #pragma unroll
    for (int i = 0; i < 8; ++i)
        #pragma unroll
        for (int j = 0; j < 4; ++j) {
            f32x4 z = {0.f, 0.f, 0.f, 0.f};
            acc[i][j] = z;
        }

    // prologue: tile T staged at {g(T-2).p2..p4, g(T-1).p1} in steady state;
    // virtual groups -2/-1 -> stage 7 half-tiles, first 4 = all of tile 0.
    STAGE_B(0, 0); STAGE_B(1, 0); STAGE_A(0, 0); STAGE_A(1, 0);
    STAGE_B(0, 1); STAGE_B(1, 1); STAGE_A(0, 1);
    asm volatile("s_waitcnt vmcnt(6)" ::: "memory"); // tile 0 (8 loads) landed
    fence_barrier();

    const int NT = K >> 6;
    bf16x8 fa[4][2], fb[4][2];

    for (int t = 0; t < NT; ++t) {
        const int p = t & 1;
        const bf16* aH = &As[p][wm][0];
        const bf16* bH = &Bs[p][wn >> 1][0];

        // ---- phase 1: fa(m0-3) + all fb ---------------------------------
        #pragma unroll
        for (int i = 0; i < 4; ++i) {
            fa[i][0] = *(const bf16x8*)(aH + i * 1024 + ra + cg0);
            fa[i][1] = *(const bf16x8*)(aH + i * 1024 + ra + cg1);
        }
        #pragma unroll
        for (int j = 0; j < 4; ++j) {
            fb[j][0] = *(const bf16x8*)(bH + rb + j * 1024 + cg0);
            fb[j][1] = *(const bf16x8*)(bH + rb + j * 1024 + cg1);
        }
        if (t + 1 < NT) STAGE_A(1, t + 1);
        fence_barrier();
        LGKM0();
        __builtin_amdgcn_s_setprio(1);
        #pragma unroll
        for (int ks = 0; ks < 2; ++ks)
            #pragma unroll
            for (int i = 0; i < 4; ++i)
                #pragma unroll
                for (int j = 0; j < 2; ++j)
                    acc[i][j] = __builtin_amdgcn_mfma_f32_16x16x32_bf16(
                        fa[i][ks], fb[j][ks], acc[i][j], 0, 0, 0);
        __builtin_amdgcn_s_setprio(0);
        fence_barrier();

        // ---- phase 2 -----------------------------------------------------
        if (t + 2 < NT) STAGE_B(0, t + 2);   // B(t) fully read in p1
        fence_barrier();
        LGKM0();
        __builtin_amdgcn_s_setprio(1);
        #pragma unroll
        for (int ks = 0; ks < 2; ++ks)
            #pragma unroll
            for (int i = 0; i < 4; ++i)
                #pragma unroll
                for (int j = 2; j < 4; ++j)
                    acc[i][j] = __builtin_amdgcn_mfma_f32_16x16x32_bf16(
                        fa[i][ks], fb[j][ks], acc[i][j], 0, 0, 0);
        __builtin_amdgcn_s_setprio(0);
        fence_barrier();

        // ---- phase 3: fa(m4-7) ------------------------------------------
        #pragma unroll
        for (int i = 0; i < 4; ++i) {
            fa[i][0] = *(const bf16x8*)(aH + (i + 4) * 1024 + ra + cg0);
            fa[i][1] = *(const bf16x8*)(aH + (i + 4) * 1024 + ra + cg1);
        }
        if (t + 2 < NT) STAGE_B(1, t + 2);
        fence_barrier();
        LGKM0();
        __builtin_amdgcn_s_setprio(1);
        #pragma unroll
        for (int ks = 0; ks < 2; ++ks)
            #pragma unroll
            for (int i = 0; i < 4; ++i)
                #pragma unroll
                for (int j = 2; j < 4; ++j)
                    acc[i + 4][j] = __builtin_amdgcn_mfma_f32_16x16x32_bf16(
                        fa[i][ks], fb[j][ks], acc[i + 4][j], 0, 0, 0);
        __builtin_amdgcn_s_setprio(0);
        fence_barrier();

        // ---- phase 4: the ONLY vmcnt of the K-tile ----------------------
        if (t + 2 < NT) {
            STAGE_A(0, t + 2);               // A(t) fully read by end p3
            // 3 half-tiles (p2,p3,p4 stages) stay in flight; A-hi(t+1)
            // from p1 and everything older is guaranteed landed.
            asm volatile("s_waitcnt vmcnt(6)" ::: "memory");
        } else {
            asm volatile("s_waitcnt vmcnt(0)" ::: "memory"); // tail drain
        }
        fence_barrier();
        __builtin_amdgcn_s_setprio(1);
        #pragma unroll
        for (int ks = 0; ks < 2; ++ks)
            #pragma unroll
            for (int i = 0; i < 4; ++i)
                #pragma unroll
                for (int j = 0; j < 2; ++j)
                    acc[i + 4][j] = __builtin_amdgcn_mfma_f32_16x16x32_bf16(
                        fa[i][ks], fb[j][ks], acc[i + 4][j], 0, 0, 0);
        __builtin_amdgcn_s_setprio(0);
        fence_barrier();
    }

    // epilogue: C/D layout col = lane&15, row = (lane>>4)*4 + reg (verified)
    const int er = bm * 256 + wm * 128 + (lane >> 4) * 4;
    const int ec = bn * 256 + wn * 64 + fr;
    #pragma unroll
    for (int j = 0; j < 4; ++j) {
        const int col = ec + j * 16;
        const float bv = bias[col];
        #pragma unroll
        for (int i = 0; i < 8; ++i) {
            #pragma unroll
            for (int r = 0; r < 4; ++r) {
                const int row = er + i * 16 + r;
                float v = acc[i][j][r] + bv;
                if (RELU) v = v > 0.f ? v : 0.f;
                C[(size_t)row * N + col] = (OUT_T)v;
            }
        }
    }
}

// ---------------------------------------------------------------------------
extern "C" void kernel_launch(void* const* d_in, const int* in_sizes, int n_in,
                              void* d_out, int out_size, void* d_ws, size_t ws_size,
                              hipStream_t stream) {
    const float* x1           = (const float*)d_in[0];
    const int*   w_up_q       = (const int*)  d_in[1];
    const float* w_up_scale   = (const float*)d_in[2];
    const float* b_up         = (const float*)d_in[3];
    const float* w_up_lora_a  = (const float*)d_in[4];
    const float* w_up_lora_b  = (const float*)d_in[5];
    const int*   w_down_q     = (const int*)  d_in[6];
    const float* w_down_scale = (const float*)d_in[7];
    const float* b_down       = (const float*)d_in[8];
    const float* w_down_lora_a= (const float*)d_in[9];
    const float* w_down_lora_b= (const float*)d_in[10];
    float* out = (float*)d_out;

    const int M = 8192, D = 2048, H = 8192;

    char* ws = (char*)d_ws;
    bf16* x1b = (bf16*)ws;                                   // M*D   (32 MB)
    bf16* wup = (bf16*)(ws + (size_t)M * D * 2);             // H*D   (32 MB)
    bf16* x2  = (bf16*)(ws + (size_t)M * D * 2 + (size_t)H * D * 2); // M*H (128 MB)
    bf16* wdn = x1b;  // reuse region 0 after gemm1 consumed x1b

    {
        int n4 = (M * D) / 4;
        cast_f32_to_bf16<<<dim3((n4 + 255) / 256), dim3(256), 0, stream>>>(x1, x1b, n4);
    }
    dequant_lora<<<dim3(D / 64, H / 64), dim3(256), 0, stream>>>(
        w_up_q, w_up_scale, w_up_lora_a, w_up_lora_b, wup, H, D);
    gemm_bt256<true, bf16><<<dim3(H / 256, M / 256), dim3(512), 0, stream>>>(
        x1b, wup, b_up, x2, M, H, D);
    dequant_lora<<<dim3(H / 64, D / 64), dim3(256), 0, stream>>>(
        w_down_q, w_down_scale, w_down_lora_a, w_down_lora_b, wdn, D, H);
    gemm_bt256<false, float><<<dim3(D / 256, M / 256), dim3(512), 0, stream>>>(
        x2, wdn, b_down, out, M, D, H);
}

// Round 2
// 784.276 us; speedup vs baseline: 1.2392x; 1.0070x over previous
//
#include <hip/hip_runtime.h>
#include <hip/hip_bf16.h>
#include <stdint.h>
#include <stddef.h>

typedef __bf16 bf16;
typedef bf16  bf16x4 __attribute__((ext_vector_type(4)));
typedef bf16  bf16x8 __attribute__((ext_vector_type(8)));
typedef float f32x4  __attribute__((ext_vector_type(4)));

// ---------------------------------------------------------------------------
// async global->LDS, 16B per lane. LDS dest is wave-uniform base + lane*16.
// ---------------------------------------------------------------------------
__device__ __forceinline__ void async_copy16(bf16* lds, const bf16* g) {
    __builtin_amdgcn_global_load_lds(
        (const __attribute__((address_space(1))) void*)g,
        (__attribute__((address_space(3))) void*)lds,
        16, 0, 0);
}

// v6: BARE sync primitives (m201 template form). v5 wrapped every barrier
// and waitcnt in asm(:::"memory"); hipcc treats memory-clobbering asm as
// may-touch-all-memory and inserts s_waitcnt vmcnt(0) before it while
// global_load_lds writes are outstanding -> every phase drained the VMEM
// queue, defeating the counted-vmcnt pipeline (measured: MfmaUtil 38% =
// the drain-to-0 signature, m218). Bare s_barrier builtin still blocks
// IR/MI motion of LDS ops (conservative intrinsic memory modeling);
// sched_barrier(0) pins scheduler order with NO memory semantics.
__device__ __forceinline__ void bar() { __builtin_amdgcn_s_barrier(); }
#define SFENCE() __builtin_amdgcn_sched_barrier(0)
#define WAIT_LGKM0() do { asm volatile("s_waitcnt lgkmcnt(0)"); SFENCE(); } while (0)
#define WAIT_VM6()   do { asm volatile("s_waitcnt vmcnt(6)");   SFENCE(); } while (0)
#define WAIT_VM0()   do { asm volatile("s_waitcnt vmcnt(0)");   SFENCE(); } while (0)

// ---------------------------------------------------------------------------
// cast fp32 -> bf16, 4 elems/thread (unchanged)
// ---------------------------------------------------------------------------
__global__ __launch_bounds__(256) void cast_f32_to_bf16(
        const float* __restrict__ in, bf16* __restrict__ out, int n4) {
    int i = blockIdx.x * blockDim.x + threadIdx.x;
    if (i >= n4) return;
    const float4 v = *(const float4*)(in + (size_t)i * 4);
    bf16x4 o;
    o[0] = (bf16)v.x; o[1] = (bf16)v.y; o[2] = (bf16)v.z; o[3] = (bf16)v.w;
    *(bf16x4*)(out + (size_t)i * 4) = o;
}

// ---------------------------------------------------------------------------
// W_eff[n][k] = (q[n][k] - 7.5) * scale[n][k/64] + sum_r A[k][r]*Bm[r][n]
// (unchanged)
// ---------------------------------------------------------------------------
__global__ __launch_bounds__(256) void dequant_lora(
        const int*   __restrict__ q,
        const float* __restrict__ scale,
        const float* __restrict__ A,
        const float* __restrict__ Bm,
        bf16* __restrict__ out,
        int N, int K) {
    const int tid = threadIdx.x;
    const int k0 = blockIdx.x * 64;
    const int n0 = blockIdx.y * 64;
    const int kk = k0 + (tid & 15) * 4;
    const int nb = n0 + (tid >> 4) * 4;

    f32x4 Ar[4][4];
    #pragma unroll
    for (int i = 0; i < 4; ++i)
        #pragma unroll
        for (int rq = 0; rq < 4; ++rq)
            Ar[i][rq] = *(const f32x4*)&A[(size_t)(kk + i) * 16 + rq * 4];
    f32x4 Br[16];
    #pragma unroll
    for (int r = 0; r < 16; ++r)
        Br[r] = *(const f32x4*)&Bm[(size_t)r * N + nb];

    const int scol = (unsigned)k0 >> 6;
    #pragma unroll
    for (int nn = 0; nn < 4; ++nn) {
        const int n = nb + nn;
        const int4 qv = *(const int4*)&q[(size_t)n * K + kk];
        const float s = scale[(size_t)n * (K >> 6) + scol];
        float l0 = 0.f, l1 = 0.f, l2 = 0.f, l3 = 0.f;
        #pragma unroll
        for (int r = 0; r < 16; ++r) {
            const float bv = Br[r][nn];
            l0 += Ar[0][r >> 2][r & 3] * bv;
            l1 += Ar[1][r >> 2][r & 3] * bv;
            l2 += Ar[2][r >> 2][r & 3] * bv;
            l3 += Ar[3][r >> 2][r & 3] * bv;
        }
        bf16x4 o;
        o[0] = (bf16)(((float)qv.x - 7.5f) * s + l0);
        o[1] = (bf16)(((float)qv.y - 7.5f) * s + l1);
        o[2] = (bf16)(((float)qv.z - 7.5f) * s + l2);
        o[3] = (bf16)(((float)qv.w - 7.5f) * s + l3);
        *(bf16x4*)&out[(size_t)n * K + kk] = o;
    }
}

// ---------------------------------------------------------------------------
// gemm_bt256: C[m][n] = sum_k A[m][k]*B[n][k] + bias[n]  (optional ReLU)
//
// 256x256 tile, BK=64, 8 waves (2Mx4N), 8-phase schedule, counted vmcnt.
// LDS: [dbuf 2][half 2][128x64] bf16 for A and B = 128 KiB, 1 block/CU.
// Swizzle: 16B-granule column XOR (row&7), involution applied on the
// pre-swizzled GLOBAL source (LDS dest linear: global_load_lds req) and on
// the ds_read address. SQ_LDS_BANK_CONFLICT measured 0.
//
// Per K-tile t (4 phases; wave owns 128x64 out = acc[8][4]):
//   p1: ds_read fa(m0-3)+fb(all 8) | stage A-hi(t+1) | MFMA Q0(i0-3,j0-1)
//   p2:                            | stage B-lo(t+2) | MFMA Q1(i0-3,j2-3)
//   p3: ds_read fa(m4-7)           | stage B-hi(t+2) | MFMA Q2(i4-7,j2-3)
//   p4:            | stage A-lo(t+2) + vmcnt(6)      | MFMA Q3(i4-7,j0-1)
// Each phase: {reads, stage} -> bar -> lgkmcnt(0) -> setprio(1) -> 16 MFMA
// -> setprio(0) -> bar. The mid-phase lgkm0 also publishes "reads drained"
// so the end barrier makes this buffer region re-stageable. vmcnt(6) once
// per K-tile keeps 3 half-tiles in flight ACROSS barriers.
// ---------------------------------------------------------------------------
template <bool RELU, typename OUT_T>
__global__ __launch_bounds__(512, 2) void gemm_bt256(
        const bf16* __restrict__ A, const bf16* __restrict__ B,
        const float* __restrict__ bias, OUT_T* __restrict__ C,
        int M, int N, int K) {
    __shared__ __attribute__((aligned(16))) bf16 As[2][2][128 * 64];
    __shared__ __attribute__((aligned(16))) bf16 Bs[2][2][128 * 64];

    const int tid  = threadIdx.x;
    const int wave = tid >> 6;
    const int lane = tid & 63;
    const int wm   = wave >> 2;     // 0..1 : row half of the 256-tile
    const int wn   = wave & 3;      // 0..3 : 64-col slice
    const int bn   = blockIdx.x;
    const int bm   = blockIdx.y;

    // staging: thread covers 16B-granules tid (rows 0..63) and tid+512
    // (rows 64..127) of each [128][64] half-tile; source col granule
    // pre-swizzled with the same involution the reads apply.
    const int srow = tid >> 3;
    const int scol = ((tid & 7) ^ (srow & 7)) * 8;   // elems
    const bf16* gA = A + ((size_t)(bm * 256) + srow) * K + scol;
    const bf16* gB = B + ((size_t)(bn * 256) + srow) * K + scol;

    auto STAGE_A = [&](int h, int tt) {
        bf16* l = &As[tt & 1][h][wave * 512];        // wave-uniform dest
        const bf16* g = gA + (size_t)h * 128 * K + (size_t)tt * 64;
        async_copy16(l, g);
        async_copy16(l + 4096, g + (size_t)64 * K);  // rows +64
    };
    auto STAGE_B = [&](int h, int tt) {
        bf16* l = &Bs[tt & 1][h][wave * 512];
        const bf16* g = gB + (size_t)h * 128 * K + (size_t)tt * 64;
        async_copy16(l, g);
        async_copy16(l + 4096, g + (size_t)64 * K);
    };

    const int fr  = lane & 15;
    const int kq  = lane >> 4;
    const int cg0 = ((kq    ) ^ (fr & 7)) * 8;
    const int cg1 = ((kq + 4) ^ (fr & 7)) * 8;
    const int ra  = fr * 64;
    const int rb  = (wn & 1) * 4096 + fr * 64;       // 64-col offset in B half

    f32x4 acc[8][4];
    #pragma unroll
    for (int i = 0; i < 8; ++i)
        #pragma unroll
        for (int j = 0; j < 4; ++j) {
            f32x4 z = {0.f, 0.f, 0.f, 0.f};
            acc[i][j] = z;
        }

    // prologue: stage 7 half-tiles; first 4 = all of tile 0.
    STAGE_B(0, 0); STAGE_B(1, 0); STAGE_A(0, 0); STAGE_A(1, 0);
    STAGE_B(0, 1); STAGE_B(1, 1); STAGE_A(0, 1);
    WAIT_VM6();                      // tile 0 (8 loads) landed
    bar();

    const int NT = K >> 6;
    bf16x8 fa[4][2], fb[4][2];

    for (int t = 0; t < NT; ++t) {
        const int p = t & 1;
        const bf16* aH = &As[p][wm][0];
        const bf16* bH = &Bs[p][wn >> 1][0];

        // ---- phase 1: fa(m0-3) + all fb ---------------------------------
        #pragma unroll
        for (int i = 0; i < 4; ++i) {
            fa[i][0] = *(const bf16x8*)(aH + i * 1024 + ra + cg0);
            fa[i][1] = *(const bf16x8*)(aH + i * 1024 + ra + cg1);
        }
        #pragma unroll
        for (int j = 0; j < 4; ++j) {
            fb[j][0] = *(const bf16x8*)(bH + rb + j * 1024 + cg0);
            fb[j][1] = *(const bf16x8*)(bH + rb + j * 1024 + cg1);
        }
        if (t + 1 < NT) STAGE_A(1, t + 1);
        bar();
        WAIT_LGKM0();
        __builtin_amdgcn_s_setprio(1);
        #pragma unroll
        for (int ks = 0; ks < 2; ++ks)
            #pragma unroll
            for (int i = 0; i < 4; ++i)
                #pragma unroll
                for (int j = 0; j < 2; ++j)
                    acc[i][j] = __builtin_amdgcn_mfma_f32_16x16x32_bf16(
                        fa[i][ks], fb[j][ks], acc[i][j], 0, 0, 0);
        __builtin_amdgcn_s_setprio(0);
        bar();

        // ---- phase 2 -----------------------------------------------------
        if (t + 2 < NT) STAGE_B(0, t + 2);   // B(t) fully read in p1
        bar();
        WAIT_LGKM0();
        __builtin_amdgcn_s_setprio(1);
        #pragma unroll
        for (int ks = 0; ks < 2; ++ks)
            #pragma unroll
            for (int i = 0; i < 4; ++i)
                #pragma unroll
                for (int j = 2; j < 4; ++j)
                    acc[i][j] = __builtin_amdgcn_mfma_f32_16x16x32_bf16(
                        fa[i][ks], fb[j][ks], acc[i][j], 0, 0, 0);
        __builtin_amdgcn_s_setprio(0);
        bar();

        // ---- phase 3: fa(m4-7) ------------------------------------------
        #pragma unroll
        for (int i = 0; i < 4; ++i) {
            fa[i][0] = *(const bf16x8*)(aH + (i + 4) * 1024 + ra + cg0);
            fa[i][1] = *(const bf16x8*)(aH + (i + 4) * 1024 + ra + cg1);
        }
        if (t + 2 < NT) STAGE_B(1, t + 2);
        bar();
        WAIT_LGKM0();
        __builtin_amdgcn_s_setprio(1);
        #pragma unroll
        for (int ks = 0; ks < 2; ++ks)
            #pragma unroll
            for (int i = 0; i < 4; ++i)
                #pragma unroll
                for (int j = 2; j < 4; ++j)
                    acc[i + 4][j] = __builtin_amdgcn_mfma_f32_16x16x32_bf16(
                        fa[i][ks], fb[j][ks], acc[i + 4][j], 0, 0, 0);
        __builtin_amdgcn_s_setprio(0);
        bar();

        // ---- phase 4: the ONLY vmcnt of the K-tile ----------------------
        if (t + 2 < NT) {
            STAGE_A(0, t + 2);               // A(t) fully read by end p3
            WAIT_VM6();                      // keep 3 half-tiles in flight
        } else {
            WAIT_VM0();                      // tail drain
        }
        bar();
        __builtin_amdgcn_s_setprio(1);
        #pragma unroll
        for (int ks = 0; ks < 2; ++ks)
            #pragma unroll
            for (int i = 0; i < 4; ++i)
                #pragma unroll
                for (int j = 0; j < 2; ++j)
                    acc[i + 4][j] = __builtin_amdgcn_mfma_f32_16x16x32_bf16(
                        fa[i][ks], fb[j][ks], acc[i + 4][j], 0, 0, 0);
        __builtin_amdgcn_s_setprio(0);
        bar();
    }

    // epilogue: C/D layout col = lane&15, row = (lane>>4)*4 + reg (verified)
    const int er = bm * 256 + wm * 128 + (lane >> 4) * 4;
    const int ec = bn * 256 + wn * 64 + fr;
    #pragma unroll
    for (int j = 0; j < 4; ++j) {
        const int col = ec + j * 16;
        const float bv = bias[col];
        #pragma unroll
        for (int i = 0; i < 8; ++i) {
            #pragma unroll
            for (int r = 0; r < 4; ++r) {
                const int row = er + i * 16 + r;
                float v = acc[i][j][r] + bv;
                if (RELU) v = v > 0.f ? v : 0.f;
                C[(size_t)row * N + col] = (OUT_T)v;
            }
        }
    }
}

// ---------------------------------------------------------------------------
extern "C" void kernel_launch(void* const* d_in, const int* in_sizes, int n_in,
                              void* d_out, int out_size, void* d_ws, size_t ws_size,
                              hipStream_t stream) {
    const float* x1           = (const float*)d_in[0];
    const int*   w_up_q       = (const int*)  d_in[1];
    const float* w_up_scale   = (const float*)d_in[2];
    const float* b_up         = (const float*)d_in[3];
    const float* w_up_lora_a  = (const float*)d_in[4];
    const float* w_up_lora_b  = (const float*)d_in[5];
    const int*   w_down_q     = (const int*)  d_in[6];
    const float* w_down_scale = (const float*)d_in[7];
    const float* b_down       = (const float*)d_in[8];
    const float* w_down_lora_a= (const float*)d_in[9];
    const float* w_down_lora_b= (const float*)d_in[10];
    float* out = (float*)d_out;

    const int M = 8192, D = 2048, H = 8192;

    char* ws = (char*)d_ws;
    bf16* x1b = (bf16*)ws;                                   // M*D   (32 MB)
    bf16* wup = (bf16*)(ws + (size_t)M * D * 2);             // H*D   (32 MB)
    bf16* x2  = (bf16*)(ws + (size_t)M * D * 2 + (size_t)H * D * 2); // M*H (128 MB)
    bf16* wdn = x1b;  // reuse region 0 after gemm1 consumed x1b

    {
        int n4 = (M * D) / 4;
        cast_f32_to_bf16<<<dim3((n4 + 255) / 256), dim3(256), 0, stream>>>(x1, x1b, n4);
    }
    dequant_lora<<<dim3(D / 64, H / 64), dim3(256), 0, stream>>>(
        w_up_q, w_up_scale, w_up_lora_a, w_up_lora_b, wup, H, D);
    gemm_bt256<true, bf16><<<dim3(H / 256, M / 256), dim3(512), 0, stream>>>(
        x1b, wup, b_up, x2, M, H, D);
    dequant_lora<<<dim3(H / 64, D / 64), dim3(256), 0, stream>>>(
        w_down_q, w_down_scale, w_down_lora_a, w_down_lora_b, wdn, D, H);
    gemm_bt256<false, float><<<dim3(D / 256, M / 256), dim3(512), 0, stream>>>(
        x2, wdn, b_down, out, M, D, H);
}